// Round 2
// baseline (1099.906 us; speedup 1.0000x reference)
//
#include <hip/hip_runtime.h>
#include <hip/hip_bf16.h>

#define BSZ    2
#define NQ     300
#define NH     8
#define HID    256
#define NLVL   4
#define NCELL  49
#define TOTAL  21760

// ---------------------------------------------------------------------------
// Kernel 1: gate = sigmoid(tgt @ attn1_w + attn1_b)   (600 x 2048, K=256)
// grid (150, 2): 4 query-rows per block, 1024 cols per block-half.
// ---------------------------------------------------------------------------
__global__ __launch_bounds__(256) void k_gate(const float* __restrict__ tgt,
                                              const float* __restrict__ w,
                                              const float* __restrict__ bias,
                                              float* __restrict__ gate) {
    __shared__ float sm_t[4][HID];
    const int tid = threadIdx.x;
    const int r0  = blockIdx.x * 4;
    const int c0  = blockIdx.y * 1024;
    for (int i = tid; i < 4 * HID; i += 256)
        sm_t[i >> 8][i & 255] = tgt[(size_t)(r0 + (i >> 8)) * HID + (i & 255)];
    __syncthreads();
    float acc[4][4];
#pragma unroll
    for (int a = 0; a < 4; ++a)
#pragma unroll
        for (int b = 0; b < 4; ++b) acc[a][b] = 0.f;
    for (int k = 0; k < HID; ++k) {
        float t0 = sm_t[0][k], t1 = sm_t[1][k], t2 = sm_t[2][k], t3 = sm_t[3][k];
        const float* wr = w + (size_t)k * 2048 + c0 + tid;
#pragma unroll
        for (int j = 0; j < 4; ++j) {
            float wv = wr[j * 256];
            acc[0][j] += t0 * wv;
            acc[1][j] += t1 * wv;
            acc[2][j] += t2 * wv;
            acc[3][j] += t3 * wv;
        }
    }
#pragma unroll
    for (int rr = 0; rr < 4; ++rr)
#pragma unroll
        for (int j = 0; j < 4; ++j) {
            int col = c0 + j * 256 + tid;
            float v = acc[rr][j] + bias[col];
            gate[(size_t)(r0 + rr) * 2048 + col] = 1.f / (1.f + expf(-v));
        }
}

// ---------------------------------------------------------------------------
// Kernel 2: per (query, level): ROI-align -> p1 -> MLP -> tanh pts ->
//           grid_sample -> * gate -> qe.   grid (600, 4), 256 threads.
// ---------------------------------------------------------------------------
__global__ __launch_bounds__(256) void k_main(
    const float* __restrict__ memory, const float* __restrict__ refr,
    const float* __restrict__ p1w, const float* __restrict__ p1b,
    const float* __restrict__ w1, const float* __restrict__ b1,
    const float* __restrict__ w2, const float* __restrict__ b2,
    const float* __restrict__ w3, const float* __restrict__ b3,
    const float* __restrict__ w4, const float* __restrict__ b4,
    const float* __restrict__ gate, float* __restrict__ qe) {
    __shared__ float sm_roi[NCELL * HID];  // [cell][c]  (49*256*4 = 50176 B)
    __shared__ float sm_p[3136];           // p1 out [d*49+cell]; later h2/h3
    __shared__ float sm_h1[256];
    __shared__ float sm_pts[16];

    const int tid = threadIdx.x;
    const int r   = blockIdx.x;  // b*300 + q
    const int lvl = blockIdx.y;
    const int b   = r / NQ;

    const int lvl_hw[4] = {128, 64, 32, 16};
    const int lvl_s[4]  = {0, 16384, 20480, 21504};
    const int W = lvl_hw[lvl];
    const float Wf = (float)W;

    // ---- box from reference (xyxy in feature coords) ----
    const float* rp = refr + ((size_t)r * NLVL + lvl) * 6;
    float cx = rp[0], cy = rp[1];
    float dl = rp[2], dt = rp[3], dr = rp[4], db = rp[5];
    float x1 = fminf(fmaxf(cx - dl, 0.f), 1.f) * Wf;
    float y1 = fminf(fmaxf(cy - dt, 0.f), 1.f) * Wf;
    float x2 = fminf(fmaxf(cx + dr, 0.f), 1.f) * Wf;
    float y2 = fminf(fmaxf(cy + db, 0.f), 1.f) * Wf;
    const float sx = x1 - 0.5f, sy = y1 - 0.5f;
    const float bw = (x2 - x1) * (1.f / 7.f), bh = (y2 - y1) * (1.f / 7.f);

    const float* mem = memory + ((size_t)b * TOTAL + lvl_s[lvl]) * HID + tid;

    // ---- ROI align: 49 cells, 2x2 subsamples, bilinear, mean ----
    for (int cell = 0; cell < NCELL; ++cell) {
        const int ph = cell / 7, pw = cell % 7;
        float acc = 0.f;
#pragma unroll
        for (int sub = 0; sub < 4; ++sub) {
            const float ty = (float)ph + ((sub >> 1) + 0.5f) * 0.5f;
            const float tx = (float)pw + ((sub & 1) + 0.5f) * 0.5f;
            float yy = sy + bh * ty;
            float xx = sx + bw * tx;
            if (yy >= -1.f && yy <= Wf && xx >= -1.f && xx <= Wf) {
                float yc = fminf(fmaxf(yy, 0.f), Wf - 1.f);
                float xc = fminf(fmaxf(xx, 0.f), Wf - 1.f);
                float y0f = fminf(floorf(yc), Wf - 2.f);
                float x0f = fminf(floorf(xc), Wf - 2.f);
                float ly = yc - y0f, lx = xc - x0f;
                int y0 = (int)y0f, x0 = (int)x0f;
                const float* p00 = mem + (size_t)(y0 * W + x0) * HID;
                float v00 = p00[0];
                float v01 = p00[HID];
                float v10 = p00[W * HID];
                float v11 = p00[W * HID + HID];
                acc += (1.f - ly) * ((1.f - lx) * v00 + lx * v01) +
                       ly * ((1.f - lx) * v10 + lx * v11);
            }
        }
        sm_roi[cell * HID + tid] = acc * 0.25f;
    }
    __syncthreads();

    // ---- p1: 256->64 per cell; p[k] with k = d*49 + cell ----
    {
        const int d = tid & 63;
        const int grp = tid >> 6;
        const int cell0 = grp * 13;
        int off[13];
#pragma unroll
        for (int i = 0; i < 13; ++i) off[i] = min(cell0 + i, NCELL - 1) * HID;
        float acc[13];
#pragma unroll
        for (int i = 0; i < 13; ++i) acc[i] = 0.f;
        for (int c = 0; c < HID; ++c) {
            float wv = p1w[(size_t)c * 64 + d];
#pragma unroll
            for (int i = 0; i < 13; ++i) acc[i] += sm_roi[off[i] + c] * wv;
        }
        float bias = p1b[d];
#pragma unroll
        for (int i = 0; i < 13; ++i) {
            int cell = cell0 + i;
            if (cell < NCELL) sm_p[d * NCELL + cell] = fmaxf(acc[i] + bias, 0.f);
        }
    }
    __syncthreads();

    // ---- MLP layer 1: 3136 -> 256 ----
    {
        float acc = 0.f;
        const float* wcol = w1 + tid;
        for (int k = 0; k < 3136; ++k) acc += sm_p[k] * wcol[(size_t)k * 256];
        sm_h1[tid] = fmaxf(acc + b1[tid], 0.f);
    }
    __syncthreads();

    float* h2 = sm_p;        // reuse (p fully consumed)
    float* h3 = sm_p + 512;

    // ---- layer 2: 256 -> 512 ----
    {
        float a0 = 0.f, a1 = 0.f;
        for (int k = 0; k < 256; ++k) {
            float hv = sm_h1[k];
            a0 += hv * w2[(size_t)k * 512 + tid];
            a1 += hv * w2[(size_t)k * 512 + tid + 256];
        }
        h2[tid]       = fmaxf(a0 + b2[tid], 0.f);
        h2[tid + 256] = fmaxf(a1 + b2[tid + 256], 0.f);
    }
    __syncthreads();

    // ---- layer 3: 512 -> 512 ----
    {
        float a0 = 0.f, a1 = 0.f;
        for (int k = 0; k < 512; ++k) {
            float hv = h2[k];
            a0 += hv * w3[(size_t)k * 512 + tid];
            a1 += hv * w3[(size_t)k * 512 + tid + 256];
        }
        h3[tid]       = fmaxf(a0 + b3[tid], 0.f);
        h3[tid + 256] = fmaxf(a1 + b3[tid + 256], 0.f);
    }
    __syncthreads();

    // ---- layer 4: 512 -> 16, tanh ----
    if (tid < 16) {
        float acc = 0.f;
        for (int k = 0; k < 512; ++k) acc += h3[k] * w4[(size_t)k * 16 + tid];
        sm_pts[tid] = tanhf(acc + b4[tid]);
    }
    __syncthreads();

    // ---- grid_sample (zeros padding, align_corners=False) + gate ----
    const float* grow = gate + (size_t)r * (NH * HID);
    float* qrow = qe + ((size_t)r * 32 + lvl * NH) * HID;
#pragma unroll
    for (int h = 0; h < NH; ++h) {
        float gx = sm_pts[h * 2], gy = sm_pts[h * 2 + 1];
        float ix = ((gx + 1.f) * 7.f - 1.f) * 0.5f;
        float iy = ((gy + 1.f) * 7.f - 1.f) * 0.5f;
        float x0f = floorf(ix), y0f = floorf(iy);
        float lx = ix - x0f, ly = iy - y0f;
        int x0 = (int)x0f, y0 = (int)y0f;
        float v = 0.f;
#pragma unroll
        for (int dy = 0; dy < 2; ++dy) {
            int yi = y0 + dy;
            if (yi < 0 || yi >= 7) continue;
            float wy = dy ? ly : 1.f - ly;
#pragma unroll
            for (int dx = 0; dx < 2; ++dx) {
                int xi = x0 + dx;
                if (xi < 0 || xi >= 7) continue;
                float wx = dx ? lx : 1.f - lx;
                v += wy * wx * sm_roi[(yi * 7 + xi) * HID + tid];
            }
        }
        qrow[h * HID + tid] = v * grow[h * HID + tid];
    }
}

// ---------------------------------------------------------------------------
// Kernel 3: per query: logits = qe @ attn2_w + b; softmax over 32; weighted sum
// ---------------------------------------------------------------------------
__global__ __launch_bounds__(256) void k_out(const float* __restrict__ qe,
                                             const float* __restrict__ w,
                                             const float* __restrict__ bias,
                                             float* __restrict__ out) {
    __shared__ float sm_l[32];
    __shared__ float sm_e[32];
    const int tid = threadIdx.x;
    const int r = blockIdx.x;
    const float* q = qe + (size_t)r * 32 * HID;
    const int j = tid >> 3, sub = tid & 7;
    float part = 0.f;
    const int cbase = sub * 32;
    for (int c = 0; c < 32; ++c) part += q[j * HID + cbase + c] * w[cbase + c];
    part += __shfl_down(part, 4);
    part += __shfl_down(part, 2);
    part += __shfl_down(part, 1);
    if (sub == 0) sm_l[j] = part + bias[0];
    __syncthreads();
    if (tid < 32) {
        float m = -1e30f;
        for (int i = 0; i < 32; ++i) m = fmaxf(m, sm_l[i]);
        sm_e[tid] = expf(sm_l[tid] - m);
    }
    __syncthreads();
    float denom = 0.f;
    for (int i = 0; i < 32; ++i) denom += sm_e[i];
    float inv = 1.f / denom;
    float acc = 0.f;
    for (int jj = 0; jj < 32; ++jj) acc += q[jj * HID + tid] * sm_e[jj];
    out[(size_t)r * HID + tid] = acc * inv;
}

// ---------------------------------------------------------------------------
extern "C" void kernel_launch(void* const* d_in, const int* in_sizes, int n_in,
                              void* d_out, int out_size, void* d_ws, size_t ws_size,
                              hipStream_t stream) {
    const float* tgt    = (const float*)d_in[0];
    const float* memory = (const float*)d_in[1];
    const float* refr   = (const float*)d_in[2];
    // d_in[3]: level_start_index (int32) — values hardcoded as constants
    const float* p1w = (const float*)d_in[4];
    const float* p1b = (const float*)d_in[5];
    const float* w1  = (const float*)d_in[6];
    const float* b1  = (const float*)d_in[7];
    const float* w2  = (const float*)d_in[8];
    const float* b2  = (const float*)d_in[9];
    const float* w3  = (const float*)d_in[10];
    const float* b3  = (const float*)d_in[11];
    const float* w4  = (const float*)d_in[12];
    const float* b4  = (const float*)d_in[13];
    const float* a1w = (const float*)d_in[14];
    const float* a1b = (const float*)d_in[15];
    const float* a2w = (const float*)d_in[16];
    const float* a2b = (const float*)d_in[17];
    float* out = (float*)d_out;

    float* gate = (float*)d_ws;                       // 600*2048 fp32
    float* qe   = gate + (size_t)600 * 2048;          // 600*32*256 fp32

    hipLaunchKernelGGL(k_gate, dim3(150, 2), dim3(256), 0, stream, tgt, a1w, a1b, gate);
    hipLaunchKernelGGL(k_main, dim3(600, 4), dim3(256), 0, stream,
                       memory, refr, p1w, p1b, w1, b1, w2, b2, w3, b3, w4, b4, gate, qe);
    hipLaunchKernelGGL(k_out, dim3(600), dim3(256), 0, stream, qe, a2w, a2b, out);
}

// Round 3
// 666.623 us; speedup vs baseline: 1.6500x; 1.6500x over previous
//
#include <hip/hip_runtime.h>

#define NQ     300
#define NH     8
#define HID    256
#define NLVL   4
#define NCELL  49
#define TOTAL  21760

// ---------------------------------------------------------------------------
// Shared helpers: ROI box + single-cell ROI-align (float4 over 4 channels)
// ---------------------------------------------------------------------------
struct Box {
    float sx, sy, bw, bh, Wf;
    int W;
    const float* memb;  // base + lane*4 channels
};

__device__ __forceinline__ void load_box(const float* __restrict__ refr,
                                         const float* __restrict__ memory,
                                         int r, int lvl, int lane, Box& bx) {
    const int lvl_hw[4] = {128, 64, 32, 16};
    const int lvl_s[4]  = {0, 16384, 20480, 21504};
    const int b = r / NQ;
    bx.W  = lvl_hw[lvl];
    bx.Wf = (float)bx.W;
    const float* rp = refr + ((size_t)r * NLVL + lvl) * 6;
    float cx = rp[0], cy = rp[1];
    float dl = rp[2], dt = rp[3], dr = rp[4], db = rp[5];
    float x1 = fminf(fmaxf(cx - dl, 0.f), 1.f) * bx.Wf;
    float y1 = fminf(fmaxf(cy - dt, 0.f), 1.f) * bx.Wf;
    float x2 = fminf(fmaxf(cx + dr, 0.f), 1.f) * bx.Wf;
    float y2 = fminf(fmaxf(cy + db, 0.f), 1.f) * bx.Wf;
    bx.sx = x1 - 0.5f;
    bx.sy = y1 - 0.5f;
    bx.bw = (x2 - x1) * (1.f / 7.f);
    bx.bh = (y2 - y1) * (1.f / 7.f);
    bx.memb = memory + ((size_t)b * TOTAL + lvl_s[lvl]) * HID + lane * 4;
}

// ROI-align one 7x7 cell, 4 channels (lane*4..+3). Identical math to the
// validated round-2 kernel, vectorized float4 over channels.
__device__ __forceinline__ void roi_cell(const Box& bx, int cell, float4& out) {
    const int ph = cell / 7, pw = cell % 7;
    float a0 = 0.f, a1 = 0.f, a2 = 0.f, a3 = 0.f;
#pragma unroll
    for (int sub = 0; sub < 4; ++sub) {
        const float tys = (float)ph + ((sub >> 1) + 0.5f) * 0.5f;
        const float txs = (float)pw + ((sub & 1) + 0.5f) * 0.5f;
        float yy = bx.sy + bx.bh * tys;
        float xx = bx.sx + bx.bw * txs;
        if (yy >= -1.f && yy <= bx.Wf && xx >= -1.f && xx <= bx.Wf) {
            float yc = fminf(fmaxf(yy, 0.f), bx.Wf - 1.f);
            float xc = fminf(fmaxf(xx, 0.f), bx.Wf - 1.f);
            float y0f = fminf(floorf(yc), bx.Wf - 2.f);
            float x0f = fminf(floorf(xc), bx.Wf - 2.f);
            float ly = yc - y0f, lx = xc - x0f;
            int y0 = (int)y0f, x0 = (int)x0f;
            const float* p00 = bx.memb + (size_t)(y0 * bx.W + x0) * HID;
            float4 v00 = *(const float4*)p00;
            float4 v01 = *(const float4*)(p00 + HID);
            float4 v10 = *(const float4*)(p00 + bx.W * HID);
            float4 v11 = *(const float4*)(p00 + bx.W * HID + HID);
            float w00 = (1.f - ly) * (1.f - lx), w01 = (1.f - ly) * lx;
            float w10 = ly * (1.f - lx), w11 = ly * lx;
            a0 += w00 * v00.x + w01 * v01.x + w10 * v10.x + w11 * v11.x;
            a1 += w00 * v00.y + w01 * v01.y + w10 * v10.y + w11 * v11.y;
            a2 += w00 * v00.z + w01 * v01.z + w10 * v10.z + w11 * v11.z;
            a3 += w00 * v00.w + w01 * v01.w + w10 * v10.w + w11 * v11.w;
        }
    }
    out.x = a0 * 0.25f; out.y = a1 * 0.25f; out.z = a2 * 0.25f; out.w = a3 * 0.25f;
}

// ---------------------------------------------------------------------------
// Kernel 1: gate = sigmoid(tgt @ attn1_w + attn1_b)
// ---------------------------------------------------------------------------
__global__ __launch_bounds__(256) void k_gate(const float* __restrict__ tgt,
                                              const float* __restrict__ w,
                                              const float* __restrict__ bias,
                                              float* __restrict__ gate) {
    __shared__ float sm_t[4][HID];
    const int tid = threadIdx.x;
    const int r0  = blockIdx.x * 4;
    const int c0  = blockIdx.y * 1024;
    for (int i = tid; i < 4 * HID; i += 256)
        sm_t[i >> 8][i & 255] = tgt[(size_t)(r0 + (i >> 8)) * HID + (i & 255)];
    __syncthreads();
    float acc[4][4];
#pragma unroll
    for (int a = 0; a < 4; ++a)
#pragma unroll
        for (int b = 0; b < 4; ++b) acc[a][b] = 0.f;
    for (int k = 0; k < HID; ++k) {
        float t0 = sm_t[0][k], t1 = sm_t[1][k], t2 = sm_t[2][k], t3 = sm_t[3][k];
        const float* wr = w + (size_t)k * 2048 + c0 + tid;
#pragma unroll
        for (int j = 0; j < 4; ++j) {
            float wv = wr[j * 256];
            acc[0][j] += t0 * wv;
            acc[1][j] += t1 * wv;
            acc[2][j] += t2 * wv;
            acc[3][j] += t3 * wv;
        }
    }
#pragma unroll
    for (int rr = 0; rr < 4; ++rr)
#pragma unroll
        for (int j = 0; j < 4; ++j) {
            int col = c0 + j * 256 + tid;
            float v = acc[rr][j] + bias[col];
            gate[(size_t)(r0 + rr) * 2048 + col] = 1.f / (1.f + expf(-v));
        }
}

// ---------------------------------------------------------------------------
// Kernel 2: per instance (r,lvl): ROI-align (float4) + p1 -> p[inst][3136]
// ---------------------------------------------------------------------------
__global__ __launch_bounds__(256) void k_roip1(
    const float* __restrict__ memory, const float* __restrict__ refr,
    const float* __restrict__ p1w, const float* __restrict__ p1b,
    float* __restrict__ p) {
    __shared__ __align__(16) float sm_roi[NCELL * HID];
    __shared__ __align__(16) float sm_p[3136];

    const int tid  = threadIdx.x;
    const int wave = tid >> 6, lane = tid & 63;
    const int i2 = blockIdx.x;
    const int r = i2 >> 2, lvl = i2 & 3;

    Box bx;
    load_box(refr, memory, r, lvl, lane, bx);

    for (int cell = wave; cell < NCELL; cell += 4) {
        float4 o;
        roi_cell(bx, cell, o);
        *(float4*)&sm_roi[cell * HID + lane * 4] = o;
    }
    __syncthreads();

    // p1: 256->64 per cell; p[k] with k = d*49 + cell
    {
        const int d = tid & 63;
        const int grp = tid >> 6;
        const int cell0 = grp * 13;
        int off[13];
#pragma unroll
        for (int i = 0; i < 13; ++i) off[i] = min(cell0 + i, NCELL - 1) * HID;
        float acc[13];
#pragma unroll
        for (int i = 0; i < 13; ++i) acc[i] = 0.f;
        for (int c = 0; c < HID; ++c) {
            float wv = p1w[(size_t)c * 64 + d];
#pragma unroll
            for (int i = 0; i < 13; ++i) acc[i] += sm_roi[off[i] + c] * wv;
        }
        float bias = p1b[d];
#pragma unroll
        for (int i = 0; i < 13; ++i) {
            int cell = cell0 + i;
            if (cell < NCELL) sm_p[d * NCELL + cell] = fmaxf(acc[i] + bias, 0.f);
        }
    }
    __syncthreads();

    float4* p4 = (float4*)(p + (size_t)i2 * 3136);
    for (int i = tid; i < 784; i += 256) p4[i] = *(float4*)&sm_p[i * 4];
}

// ---------------------------------------------------------------------------
// Tiled fp32 GEMM: C(M,N) = relu(A(M,K) @ W(K,N) + bias). Tile 64 x TN, KC=32.
// 256 threads as 16x16; per-thread micro-tile 4 x (TN/16).
// ---------------------------------------------------------------------------
template <int TN>
__global__ __launch_bounds__(256) void k_gemm(const float* __restrict__ A,
                                              const float* __restrict__ W,
                                              const float* __restrict__ bias,
                                              float* __restrict__ C,
                                              int M, int N, int K) {
    constexpr int WN = TN / 16;
    __shared__ __align__(16) float As[32][68];   // [k][m], padded (68*4=272B, 16B-mult)
    __shared__ __align__(16) float Ws[32][TN];   // [k][n]

    const int tid = threadIdx.x;
    const int m0 = blockIdx.x * 64;
    const int n0 = blockIdx.y * TN;
    const int ty = tid >> 4, tx = tid & 15;

    float acc[4][WN];
#pragma unroll
    for (int i = 0; i < 4; ++i)
#pragma unroll
        for (int j = 0; j < WN; ++j) acc[i][j] = 0.f;

    for (int k0 = 0; k0 < K; k0 += 32) {
        // stage A: 64 rows x 32 k  (512 float4, 2/thread), transpose into As
#pragma unroll
        for (int e = tid; e < 512; e += 256) {
            int m = e >> 3;
            int kk = (e & 7) << 2;
            int mi = min(m0 + m, M - 1);
            float4 v = *(const float4*)(A + (size_t)mi * K + k0 + kk);
            As[kk + 0][m] = v.x;
            As[kk + 1][m] = v.y;
            As[kk + 2][m] = v.z;
            As[kk + 3][m] = v.w;
        }
        // stage W: 32 x TN  (TN*8 float4)
#pragma unroll
        for (int e = tid; e < TN * 8; e += 256) {
            int kk = e / (TN / 4);
            int c4 = (e % (TN / 4)) << 2;
            *(float4*)&Ws[kk][c4] = *(const float4*)(W + (size_t)(k0 + kk) * N + n0 + c4);
        }
        __syncthreads();

#pragma unroll
        for (int kc = 0; kc < 32; ++kc) {
            float4 av = *(float4*)&As[kc][ty * 4];
            float wv[WN];
#pragma unroll
            for (int j = 0; j < WN; ++j) wv[j] = Ws[kc][tx * WN + j];
            float a[4] = {av.x, av.y, av.z, av.w};
#pragma unroll
            for (int i = 0; i < 4; ++i)
#pragma unroll
                for (int j = 0; j < WN; ++j) acc[i][j] += a[i] * wv[j];
        }
        __syncthreads();
    }

#pragma unroll
    for (int i = 0; i < 4; ++i) {
        int m = m0 + ty * 4 + i;
        if (m < M) {
#pragma unroll
            for (int j = 0; j < WN; ++j) {
                int n = n0 + tx * WN + j;
                float v = acc[i][j] + bias[n];
                C[(size_t)m * N + n] = fmaxf(v, 0.f);
            }
        }
    }
}

// ---------------------------------------------------------------------------
// Layer 4: pts = tanh(h3 @ w4 + b4)   (2400 x 512 -> 2400 x 16)
// block: 16 rows x 16 cols, grid 150
// ---------------------------------------------------------------------------
__global__ __launch_bounds__(256) void k_l4(const float* __restrict__ h3,
                                            const float* __restrict__ w4,
                                            const float* __restrict__ b4,
                                            float* __restrict__ pts) {
    __shared__ __align__(16) float sm[16 * 512];
    const int tid = threadIdx.x;
    const int r0 = blockIdx.x * 16;
    const float4* src = (const float4*)(h3 + (size_t)r0 * 512);
    float4* dst = (float4*)sm;
    for (int i = tid; i < 16 * 128; i += 256) dst[i] = src[i];
    __syncthreads();
    const int row = tid >> 4, col = tid & 15;
    float acc = 0.f;
    for (int k = 0; k < 512; ++k) acc += sm[row * 512 + k] * w4[k * 16 + col];
    pts[(size_t)(r0 + row) * 16 + col] = tanhf(acc + b4[col]);
}

// ---------------------------------------------------------------------------
// Kernel: per instance: recompute needed ROI cells (deduped), grid_sample,
// gate multiply -> qe
// ---------------------------------------------------------------------------
__global__ __launch_bounds__(256) void k_sample(
    const float* __restrict__ memory, const float* __restrict__ refr,
    const float* __restrict__ pts, const float* __restrict__ gate,
    float* __restrict__ qe) {
    __shared__ __align__(16) float sm_roi[NCELL * HID];
    __shared__ float sm_hd[8][4];
    __shared__ int smNeed[NCELL];
    __shared__ int smList[NCELL];
    __shared__ int smCnt;

    const int tid = threadIdx.x;
    const int wave = tid >> 6, lane = tid & 63;
    const int i2 = blockIdx.x;
    const int r = i2 >> 2, lvl = i2 & 3;

    Box bx;
    load_box(refr, memory, r, lvl, lane, bx);

    if (tid < NCELL) smNeed[tid] = 0;
    __syncthreads();
    if (tid < 8) {
        float gx = pts[(size_t)i2 * 16 + tid * 2];
        float gy = pts[(size_t)i2 * 16 + tid * 2 + 1];
        float ix = ((gx + 1.f) * 7.f - 1.f) * 0.5f;
        float iy = ((gy + 1.f) * 7.f - 1.f) * 0.5f;
        float x0f = floorf(ix), y0f = floorf(iy);
        sm_hd[tid][0] = x0f;
        sm_hd[tid][1] = y0f;
        sm_hd[tid][2] = ix - x0f;
        sm_hd[tid][3] = iy - y0f;
        int x0 = (int)x0f, y0 = (int)y0f;
#pragma unroll
        for (int dy = 0; dy < 2; ++dy)
#pragma unroll
            for (int dx = 0; dx < 2; ++dx) {
                int xi = x0 + dx, yi = y0 + dy;
                if (xi >= 0 && xi < 7 && yi >= 0 && yi < 7) smNeed[yi * 7 + xi] = 1;
            }
    }
    __syncthreads();
    if (tid == 0) {
        int c = 0;
        for (int i = 0; i < NCELL; ++i)
            if (smNeed[i]) smList[c++] = i;
        smCnt = c;
    }
    __syncthreads();

    const int nc = smCnt;
    for (int li = wave; li < nc; li += 4) {
        int cell = smList[li];
        float4 o;
        roi_cell(bx, cell, o);
        *(float4*)&sm_roi[cell * HID + lane * 4] = o;
    }
    __syncthreads();

    const float* grow = gate + (size_t)r * 2048;
    float* qrow = qe + ((size_t)r * 32 + lvl * 8) * HID;
#pragma unroll
    for (int h = 0; h < NH; ++h) {
        float x0f = sm_hd[h][0], y0f = sm_hd[h][1];
        float lx = sm_hd[h][2], ly = sm_hd[h][3];
        int x0 = (int)x0f, y0 = (int)y0f;
        float v = 0.f;
#pragma unroll
        for (int dy = 0; dy < 2; ++dy) {
            int yi = y0 + dy;
            if (yi < 0 || yi >= 7) continue;
            float wy = dy ? ly : 1.f - ly;
#pragma unroll
            for (int dx = 0; dx < 2; ++dx) {
                int xi = x0 + dx;
                if (xi < 0 || xi >= 7) continue;
                float wx = dx ? lx : 1.f - lx;
                v += wy * wx * sm_roi[(yi * 7 + xi) * HID + tid];
            }
        }
        qrow[h * HID + tid] = v * grow[h * HID + tid];
    }
}

// ---------------------------------------------------------------------------
// Kernel: per query: logits = qe @ attn2_w + b; softmax over 32; weighted sum
// ---------------------------------------------------------------------------
__global__ __launch_bounds__(256) void k_out(const float* __restrict__ qe,
                                             const float* __restrict__ w,
                                             const float* __restrict__ bias,
                                             float* __restrict__ out) {
    __shared__ float sm_l[32];
    __shared__ float sm_e[32];
    const int tid = threadIdx.x;
    const int r = blockIdx.x;
    const float* q = qe + (size_t)r * 32 * HID;
    const int j = tid >> 3, sub = tid & 7;
    float part = 0.f;
    const int cbase = sub * 32;
    for (int c = 0; c < 32; ++c) part += q[j * HID + cbase + c] * w[cbase + c];
    part += __shfl_down(part, 4);
    part += __shfl_down(part, 2);
    part += __shfl_down(part, 1);
    if (sub == 0) sm_l[j] = part + bias[0];
    __syncthreads();
    if (tid < 32) {
        float m = -1e30f;
        for (int i = 0; i < 32; ++i) m = fmaxf(m, sm_l[i]);
        sm_e[tid] = expf(sm_l[tid] - m);
    }
    __syncthreads();
    float denom = 0.f;
    for (int i = 0; i < 32; ++i) denom += sm_e[i];
    float inv = 1.f / denom;
    float acc = 0.f;
    for (int jj = 0; jj < 32; ++jj) acc += q[jj * HID + tid] * sm_e[jj];
    out[(size_t)r * HID + tid] = acc * inv;
}

// ---------------------------------------------------------------------------
extern "C" void kernel_launch(void* const* d_in, const int* in_sizes, int n_in,
                              void* d_out, int out_size, void* d_ws, size_t ws_size,
                              hipStream_t stream) {
    const float* tgt    = (const float*)d_in[0];
    const float* memory = (const float*)d_in[1];
    const float* refr   = (const float*)d_in[2];
    const float* p1w = (const float*)d_in[4];
    const float* p1b = (const float*)d_in[5];
    const float* w1  = (const float*)d_in[6];
    const float* b1  = (const float*)d_in[7];
    const float* w2  = (const float*)d_in[8];
    const float* b2  = (const float*)d_in[9];
    const float* w3  = (const float*)d_in[10];
    const float* b3  = (const float*)d_in[11];
    const float* w4  = (const float*)d_in[12];
    const float* b4  = (const float*)d_in[13];
    const float* a1w = (const float*)d_in[14];
    const float* a1b = (const float*)d_in[15];
    const float* a2w = (const float*)d_in[16];
    const float* a2b = (const float*)d_in[17];
    float* out = (float*)d_out;

    float* gate = (float*)d_ws;                       //  600*2048
    float* p    = gate + (size_t)600 * 2048;          // 2400*3136
    float* h1   = p    + (size_t)2400 * 3136;         // 2400*256
    float* h2   = h1   + (size_t)2400 * 256;          // 2400*512
    float* h3   = h2   + (size_t)2400 * 512;          // 2400*512
    float* pts  = h3   + (size_t)2400 * 512;          // 2400*16
    float* qe   = pts  + (size_t)2400 * 16;           //  600*32*256

    hipLaunchKernelGGL(k_gate, dim3(150, 2), dim3(256), 0, stream, tgt, a1w, a1b, gate);
    hipLaunchKernelGGL(k_roip1, dim3(2400), dim3(256), 0, stream,
                       memory, refr, p1w, p1b, p);
    hipLaunchKernelGGL((k_gemm<32>), dim3(38, 8), dim3(256), 0, stream,
                       p, w1, b1, h1, 2400, 256, 3136);
    hipLaunchKernelGGL((k_gemm<64>), dim3(38, 8), dim3(256), 0, stream,
                       h1, w2, b2, h2, 2400, 512, 256);
    hipLaunchKernelGGL((k_gemm<64>), dim3(38, 8), dim3(256), 0, stream,
                       h2, w3, b3, h3, 2400, 512, 512);
    hipLaunchKernelGGL(k_l4, dim3(150), dim3(256), 0, stream, h3, w4, b4, pts);
    hipLaunchKernelGGL(k_sample, dim3(2400), dim3(256), 0, stream,
                       memory, refr, pts, gate, qe);
    hipLaunchKernelGGL(k_out, dim3(600), dim3(256), 0, stream, qe, a2w, a2b, out);
}

// Round 4
// 534.474 us; speedup vs baseline: 2.0579x; 1.2472x over previous
//
#include <hip/hip_runtime.h>
#include <hip/hip_bf16.h>

#define NQ     300
#define NH     8
#define HID    256
#define NLVL   4
#define NCELL  49
#define TOTAL  21760

typedef unsigned short ushort_t;
typedef __attribute__((ext_vector_type(8))) short short8;
typedef __attribute__((ext_vector_type(4))) float floatx4;

__device__ __forceinline__ float bfbits2f(ushort_t u) {
    union { unsigned int i; float f; } x;
    x.i = ((unsigned int)u) << 16;
    return x.f;
}
__device__ __forceinline__ void split_bf(float v, ushort_t& hi, ushort_t& lo) {
    __hip_bfloat16 h = __float2bfloat16(v);
    hi = *(ushort_t*)&h;
    float hv = __bfloat162float(h);
    __hip_bfloat16 l = __float2bfloat16(v - hv);
    lo = *(ushort_t*)&l;
}

// ---------------------------------------------------------------------------
// ROI helpers (validated in rounds 2-3)
// ---------------------------------------------------------------------------
struct Box {
    float sx, sy, bw, bh, Wf;
    int W;
    const float* memb;
};

__device__ __forceinline__ void load_box(const float* __restrict__ refr,
                                         const float* __restrict__ memory,
                                         int r, int lvl, int lane, Box& bx) {
    const int lvl_hw[4] = {128, 64, 32, 16};
    const int lvl_s[4]  = {0, 16384, 20480, 21504};
    const int b = r / NQ;
    bx.W  = lvl_hw[lvl];
    bx.Wf = (float)bx.W;
    const float* rp = refr + ((size_t)r * NLVL + lvl) * 6;
    float cx = rp[0], cy = rp[1];
    float dl = rp[2], dt = rp[3], dr = rp[4], db = rp[5];
    float x1 = fminf(fmaxf(cx - dl, 0.f), 1.f) * bx.Wf;
    float y1 = fminf(fmaxf(cy - dt, 0.f), 1.f) * bx.Wf;
    float x2 = fminf(fmaxf(cx + dr, 0.f), 1.f) * bx.Wf;
    float y2 = fminf(fmaxf(cy + db, 0.f), 1.f) * bx.Wf;
    bx.sx = x1 - 0.5f;
    bx.sy = y1 - 0.5f;
    bx.bw = (x2 - x1) * (1.f / 7.f);
    bx.bh = (y2 - y1) * (1.f / 7.f);
    bx.memb = memory + ((size_t)b * TOTAL + lvl_s[lvl]) * HID + lane * 4;
}

__device__ __forceinline__ void roi_cell(const Box& bx, int cell, float4& out) {
    const int ph = cell / 7, pw = cell % 7;
    float a0 = 0.f, a1 = 0.f, a2 = 0.f, a3 = 0.f;
#pragma unroll
    for (int sub = 0; sub < 4; ++sub) {
        const float tys = (float)ph + ((sub >> 1) + 0.5f) * 0.5f;
        const float txs = (float)pw + ((sub & 1) + 0.5f) * 0.5f;
        float yy = bx.sy + bx.bh * tys;
        float xx = bx.sx + bx.bw * txs;
        if (yy >= -1.f && yy <= bx.Wf && xx >= -1.f && xx <= bx.Wf) {
            float yc = fminf(fmaxf(yy, 0.f), bx.Wf - 1.f);
            float xc = fminf(fmaxf(xx, 0.f), bx.Wf - 1.f);
            float y0f = fminf(floorf(yc), bx.Wf - 2.f);
            float x0f = fminf(floorf(xc), bx.Wf - 2.f);
            float ly = yc - y0f, lx = xc - x0f;
            int y0 = (int)y0f, x0 = (int)x0f;
            const float* p00 = bx.memb + (size_t)(y0 * bx.W + x0) * HID;
            float4 v00 = *(const float4*)p00;
            float4 v01 = *(const float4*)(p00 + HID);
            float4 v10 = *(const float4*)(p00 + bx.W * HID);
            float4 v11 = *(const float4*)(p00 + bx.W * HID + HID);
            float w00 = (1.f - ly) * (1.f - lx), w01 = (1.f - ly) * lx;
            float w10 = ly * (1.f - lx), w11 = ly * lx;
            a0 += w00 * v00.x + w01 * v01.x + w10 * v10.x + w11 * v11.x;
            a1 += w00 * v00.y + w01 * v01.y + w10 * v10.y + w11 * v11.y;
            a2 += w00 * v00.z + w01 * v01.z + w10 * v10.z + w11 * v11.z;
            a3 += w00 * v00.w + w01 * v01.w + w10 * v10.w + w11 * v11.w;
        }
    }
    out.x = a0 * 0.25f; out.y = a1 * 0.25f; out.z = a2 * 0.25f; out.w = a3 * 0.25f;
}

// ---------------------------------------------------------------------------
// Elementwise hi/lo split (for tgt)
// ---------------------------------------------------------------------------
__global__ __launch_bounds__(256) void k_esplit(const float* __restrict__ x,
                                                ushort_t* __restrict__ hi,
                                                ushort_t* __restrict__ lo, int n) {
    int i = blockIdx.x * 256 + threadIdx.x;
    if (i < n) {
        ushort_t h, l;
        split_bf(x[i], h, l);
        hi[i] = h; lo[i] = l;
    }
}

// ---------------------------------------------------------------------------
// Transpose + hi/lo split: W[k][n] fp32 -> WT_hi/lo [n][k] bf16.
// PERM=1 (w1): source k = (k'&63)*49 + (k'>>6)  [p layout k' = cell*64+d]
// K, N multiples of 64.
// ---------------------------------------------------------------------------
template <int PERM>
__global__ __launch_bounds__(256) void k_tsplit(const float* __restrict__ W,
                                                ushort_t* __restrict__ TH,
                                                ushort_t* __restrict__ TL,
                                                int K, int N) {
    __shared__ float sm[64][65];
    const int tid = threadIdx.x;
    const int kb = blockIdx.x * 64, nb = blockIdx.y * 64;
    for (int e = tid; e < 64 * 64; e += 256) {
        int kk = e >> 6, nn = e & 63;
        int kp = kb + kk;
        int ks = PERM ? ((kp & 63) * 49 + (kp >> 6)) : kp;
        sm[kk][nn] = W[(size_t)ks * N + nb + nn];
    }
    __syncthreads();
    for (int e = tid; e < 64 * 64; e += 256) {
        int nn = e >> 6, kk = e & 63;
        ushort_t h, l;
        split_bf(sm[kk][nn], h, l);
        size_t o = (size_t)(nb + nn) * K + kb + kk;
        TH[o] = h; TL[o] = l;
    }
}

// ---------------------------------------------------------------------------
// bf16x3 MFMA GEMM: C(M,N) = epi(A(M,K) @ W^T(N,K) + bias)
// A given as hi/lo bf16 [m][k]; W as hi/lo bf16 [n][k].
// Tile 64x64, 256 threads = 4 waves; wave w computes rows [w*16,w*16+16).
// EPI: 0 = relu -> hi/lo bf16 ; 1 = relu -> fp32 ; 2 = sigmoid -> fp32
// Requires K%32==0, N%64==0.
// ---------------------------------------------------------------------------
template <int EPI>
__global__ __launch_bounds__(256) void k_gmfma(
    const ushort_t* __restrict__ AH, const ushort_t* __restrict__ AL,
    const ushort_t* __restrict__ WH, const ushort_t* __restrict__ WL,
    const float* __restrict__ bias, float* __restrict__ Cf,
    ushort_t* __restrict__ CH, ushort_t* __restrict__ CL,
    int M, int N, int K) {
    __shared__ ushort_t As[2][64][40];  // [hi/lo][m][k], row 80B (bank-safe)
    __shared__ ushort_t Ws[2][64][40];  // [hi/lo][n][k]

    const int tid = threadIdx.x;
    const int m0 = blockIdx.x * 64, n0 = blockIdx.y * 64;
    const int wv = tid >> 6, ln = tid & 63;
    const int row = tid >> 2, kc = tid & 3;  // staging map
    const int gm = min(m0 + row, M - 1);
    const int gn = n0 + row;
    const int arow = wv * 16 + (ln & 15);
    const int koff = (ln >> 4) * 8;

    floatx4 acc[4];
#pragma unroll
    for (int t = 0; t < 4; ++t) acc[t] = (floatx4){0.f, 0.f, 0.f, 0.f};

    for (int k0 = 0; k0 < K; k0 += 32) {
        *(uint4*)&As[0][row][kc * 8] = *(const uint4*)(AH + (size_t)gm * K + k0 + kc * 8);
        *(uint4*)&As[1][row][kc * 8] = *(const uint4*)(AL + (size_t)gm * K + k0 + kc * 8);
        *(uint4*)&Ws[0][row][kc * 8] = *(const uint4*)(WH + (size_t)gn * K + k0 + kc * 8);
        *(uint4*)&Ws[1][row][kc * 8] = *(const uint4*)(WL + (size_t)gn * K + k0 + kc * 8);
        __syncthreads();

        short8 aH = *(short8*)&As[0][arow][koff];
        short8 aL = *(short8*)&As[1][arow][koff];
#pragma unroll
        for (int t = 0; t < 4; ++t) {
            short8 wH = *(short8*)&Ws[0][t * 16 + (ln & 15)][koff];
            short8 wL = *(short8*)&Ws[1][t * 16 + (ln & 15)][koff];
            acc[t] = __builtin_amdgcn_mfma_f32_16x16x32_bf16(aH, wH, acc[t], 0, 0, 0);
            acc[t] = __builtin_amdgcn_mfma_f32_16x16x32_bf16(aH, wL, acc[t], 0, 0, 0);
            acc[t] = __builtin_amdgcn_mfma_f32_16x16x32_bf16(aL, wH, acc[t], 0, 0, 0);
        }
        __syncthreads();
    }

    // C/D: col = ln&15, row = (ln>>4)*4 + reg   [m89-verified]
#pragma unroll
    for (int t = 0; t < 4; ++t) {
        int n = n0 + t * 16 + (ln & 15);
        float bv = bias[n];
#pragma unroll
        for (int reg = 0; reg < 4; ++reg) {
            int m = m0 + wv * 16 + (ln >> 4) * 4 + reg;
            if (m < M) {
                float v = acc[t][reg] + bv;
                if (EPI == 0) {
                    v = fmaxf(v, 0.f);
                    ushort_t h, l;
                    split_bf(v, h, l);
                    CH[(size_t)m * N + n] = h;
                    CL[(size_t)m * N + n] = l;
                } else if (EPI == 1) {
                    Cf[(size_t)m * N + n] = fmaxf(v, 0.f);
                } else {
                    Cf[(size_t)m * N + n] = 1.f / (1.f + expf(-v));
                }
            }
        }
    }
}

// ---------------------------------------------------------------------------
// Per instance: ROI-align -> roi (bf16, global) + p1 -> p hi/lo (k'=cell*64+d)
// ---------------------------------------------------------------------------
__global__ __launch_bounds__(256) void k_roip1(
    const float* __restrict__ memory, const float* __restrict__ refr,
    const float* __restrict__ p1w, const float* __restrict__ p1b,
    ushort_t* __restrict__ roi, ushort_t* __restrict__ pH,
    ushort_t* __restrict__ pL) {
    __shared__ __align__(16) float sm_roi[NCELL * HID];  // 50176 B -> 3 blk/CU

    const int tid  = threadIdx.x;
    const int wave = tid >> 6, lane = tid & 63;
    const int i2 = blockIdx.x;
    const int r = i2 >> 2, lvl = i2 & 3;

    Box bx;
    load_box(refr, memory, r, lvl, lane, bx);

    ushort_t* rbase = roi + (size_t)i2 * NCELL * HID;
    for (int cell = wave; cell < NCELL; cell += 4) {
        float4 o;
        roi_cell(bx, cell, o);
        *(float4*)&sm_roi[cell * HID + lane * 4] = o;
        __hip_bfloat16 b0 = __float2bfloat16(o.x), b1 = __float2bfloat16(o.y);
        __hip_bfloat16 b2 = __float2bfloat16(o.z), b3 = __float2bfloat16(o.w);
        ushort4 pk;
        pk.x = *(ushort_t*)&b0; pk.y = *(ushort_t*)&b1;
        pk.z = *(ushort_t*)&b2; pk.w = *(ushort_t*)&b3;
        *(ushort4*)&rbase[cell * HID + lane * 4] = pk;
    }
    __syncthreads();

    // p1: 256->64 per cell; output k' = cell*64 + d (coalesced 128B stores)
    {
        const int d = tid & 63;
        const int grp = tid >> 6;
        const int cell0 = grp * 13;
        int off[13];
#pragma unroll
        for (int i = 0; i < 13; ++i) off[i] = min(cell0 + i, NCELL - 1) * HID;
        float acc[13];
#pragma unroll
        for (int i = 0; i < 13; ++i) acc[i] = 0.f;
        for (int c = 0; c < HID; ++c) {
            float wv = p1w[(size_t)c * 64 + d];
#pragma unroll
            for (int i = 0; i < 13; ++i) acc[i] += sm_roi[off[i] + c] * wv;
        }
        float bias = p1b[d];
        size_t pbase = (size_t)i2 * 3136;
#pragma unroll
        for (int i = 0; i < 13; ++i) {
            int cell = cell0 + i;
            if (cell < NCELL) {
                float v = fmaxf(acc[i] + bias, 0.f);
                ushort_t h, l;
                split_bf(v, h, l);
                pH[pbase + cell * 64 + d] = h;
                pL[pbase + cell * 64 + d] = l;
            }
        }
    }
}

// ---------------------------------------------------------------------------
// Layer 4: pts = tanh(h3 @ w4 + b4)   (2400 x 512 -> 2400 x 16)
// ---------------------------------------------------------------------------
__global__ __launch_bounds__(256) void k_l4(const float* __restrict__ h3,
                                            const float* __restrict__ w4,
                                            const float* __restrict__ b4,
                                            float* __restrict__ pts) {
    __shared__ __align__(16) float sm[16 * 512];
    const int tid = threadIdx.x;
    const int r0 = blockIdx.x * 16;
    const float4* src = (const float4*)(h3 + (size_t)r0 * 512);
    float4* dst = (float4*)sm;
    for (int i = tid; i < 16 * 128; i += 256) dst[i] = src[i];
    __syncthreads();
    const int row = tid >> 4, col = tid & 15;
    float acc = 0.f;
    for (int k = 0; k < 512; ++k) acc += sm[row * 512 + k] * w4[k * 16 + col];
    pts[(size_t)(r0 + row) * 16 + col] = tanhf(acc + b4[col]);
}

// ---------------------------------------------------------------------------
// grid_sample from stored roi (bf16) + gate multiply -> qe
// ---------------------------------------------------------------------------
__global__ __launch_bounds__(256) void k_sample(
    const ushort_t* __restrict__ roi, const float* __restrict__ pts,
    const float* __restrict__ gate, float* __restrict__ qe) {
    __shared__ float sm_hd[8][4];
    const int tid = threadIdx.x;
    const int i2 = blockIdx.x;
    const int r = i2 >> 2, lvl = i2 & 3;

    if (tid < 8) {
        float gx = pts[(size_t)i2 * 16 + tid * 2];
        float gy = pts[(size_t)i2 * 16 + tid * 2 + 1];
        float ix = ((gx + 1.f) * 7.f - 1.f) * 0.5f;
        float iy = ((gy + 1.f) * 7.f - 1.f) * 0.5f;
        float x0f = floorf(ix), y0f = floorf(iy);
        sm_hd[tid][0] = x0f;
        sm_hd[tid][1] = y0f;
        sm_hd[tid][2] = ix - x0f;
        sm_hd[tid][3] = iy - y0f;
    }
    __syncthreads();

    const ushort_t* rbase = roi + (size_t)i2 * NCELL * HID;
    const float* grow = gate + (size_t)r * 2048;
    float* qrow = qe + ((size_t)r * 32 + lvl * 8) * HID;
#pragma unroll
    for (int h = 0; h < NH; ++h) {
        float x0f = sm_hd[h][0], y0f = sm_hd[h][1];
        float lx = sm_hd[h][2], ly = sm_hd[h][3];
        int x0 = (int)x0f, y0 = (int)y0f;
        float v = 0.f;
#pragma unroll
        for (int dy = 0; dy < 2; ++dy) {
            int yi = y0 + dy;
            if (yi < 0 || yi >= 7) continue;
            float wy = dy ? ly : 1.f - ly;
#pragma unroll
            for (int dx = 0; dx < 2; ++dx) {
                int xi = x0 + dx;
                if (xi < 0 || xi >= 7) continue;
                float wx = dx ? lx : 1.f - lx;
                v += wy * wx * bfbits2f(rbase[(yi * 7 + xi) * HID + tid]);
            }
        }
        qrow[h * HID + tid] = v * grow[h * HID + tid];
    }
}

// ---------------------------------------------------------------------------
// Final: logits = qe @ attn2_w + b; softmax over 32; weighted sum
// ---------------------------------------------------------------------------
__global__ __launch_bounds__(256) void k_out(const float* __restrict__ qe,
                                             const float* __restrict__ w,
                                             const float* __restrict__ bias,
                                             float* __restrict__ out) {
    __shared__ float sm_l[32];
    __shared__ float sm_e[32];
    const int tid = threadIdx.x;
    const int r = blockIdx.x;
    const float* q = qe + (size_t)r * 32 * HID;
    const int j = tid >> 3, sub = tid & 7;
    float part = 0.f;
    const int cbase = sub * 32;
    for (int c = 0; c < 32; ++c) part += q[j * HID + cbase + c] * w[cbase + c];
    part += __shfl_down(part, 4);
    part += __shfl_down(part, 2);
    part += __shfl_down(part, 1);
    if (sub == 0) sm_l[j] = part + bias[0];
    __syncthreads();
    if (tid < 32) {
        float m = -1e30f;
        for (int i = 0; i < 32; ++i) m = fmaxf(m, sm_l[i]);
        sm_e[tid] = expf(sm_l[tid] - m);
    }
    __syncthreads();
    float denom = 0.f;
    for (int i = 0; i < 32; ++i) denom += sm_e[i];
    float inv = 1.f / denom;
    float acc = 0.f;
    for (int jj = 0; jj < 32; ++jj) acc += q[jj * HID + tid] * sm_e[jj];
    out[(size_t)r * HID + tid] = acc * inv;
}

// ---------------------------------------------------------------------------
extern "C" void kernel_launch(void* const* d_in, const int* in_sizes, int n_in,
                              void* d_out, int out_size, void* d_ws, size_t ws_size,
                              hipStream_t stream) {
    const float* tgt    = (const float*)d_in[0];
    const float* memory = (const float*)d_in[1];
    const float* refr   = (const float*)d_in[2];
    const float* p1w = (const float*)d_in[4];
    const float* p1b = (const float*)d_in[5];
    const float* w1  = (const float*)d_in[6];
    const float* b1  = (const float*)d_in[7];
    const float* w2  = (const float*)d_in[8];
    const float* b2  = (const float*)d_in[9];
    const float* w3  = (const float*)d_in[10];
    const float* b3  = (const float*)d_in[11];
    const float* w4  = (const float*)d_in[12];
    const float* b4  = (const float*)d_in[13];
    const float* a1w = (const float*)d_in[14];
    const float* a1b = (const float*)d_in[15];
    const float* a2w = (const float*)d_in[16];
    const float* a2b = (const float*)d_in[17];
    float* out = (float*)d_out;

    size_t off = 0;
    auto alloc = [&](size_t bytes) {
        void* p = (char*)d_ws + off;
        off += (bytes + 255) & ~(size_t)255;
        return p;
    };
    float*    gate  = (float*)alloc((size_t)600 * 2048 * 4);
    ushort_t* roi   = (ushort_t*)alloc((size_t)2400 * NCELL * HID * 2);
    ushort_t* pHb   = (ushort_t*)alloc((size_t)2400 * 3136 * 2);
    ushort_t* pLb   = (ushort_t*)alloc((size_t)2400 * 3136 * 2);
    ushort_t* h1H   = (ushort_t*)alloc((size_t)2400 * 256 * 2);
    ushort_t* h1L   = (ushort_t*)alloc((size_t)2400 * 256 * 2);
    ushort_t* h2H   = (ushort_t*)alloc((size_t)2400 * 512 * 2);
    ushort_t* h2L   = (ushort_t*)alloc((size_t)2400 * 512 * 2);
    float*    h3    = (float*)alloc((size_t)2400 * 512 * 4);
    float*    pts   = (float*)alloc((size_t)2400 * 16 * 4);
    float*    qe    = (float*)alloc((size_t)600 * 32 * 256 * 4);
    ushort_t* tgtH  = (ushort_t*)alloc((size_t)600 * 256 * 2);
    ushort_t* tgtL  = (ushort_t*)alloc((size_t)600 * 256 * 2);
    ushort_t* a1wTH = (ushort_t*)alloc((size_t)2048 * 256 * 2);
    ushort_t* a1wTL = (ushort_t*)alloc((size_t)2048 * 256 * 2);
    ushort_t* w1TH  = (ushort_t*)alloc((size_t)256 * 3136 * 2);
    ushort_t* w1TL  = (ushort_t*)alloc((size_t)256 * 3136 * 2);
    ushort_t* w2TH  = (ushort_t*)alloc((size_t)512 * 256 * 2);
    ushort_t* w2TL  = (ushort_t*)alloc((size_t)512 * 256 * 2);
    ushort_t* w3TH  = (ushort_t*)alloc((size_t)512 * 512 * 2);
    ushort_t* w3TL  = (ushort_t*)alloc((size_t)512 * 512 * 2);

    // weight prep
    hipLaunchKernelGGL(k_esplit, dim3(600), dim3(256), 0, stream,
                       tgt, tgtH, tgtL, 600 * 256);
    hipLaunchKernelGGL((k_tsplit<0>), dim3(4, 32), dim3(256), 0, stream,
                       a1w, a1wTH, a1wTL, 256, 2048);
    hipLaunchKernelGGL((k_tsplit<1>), dim3(49, 4), dim3(256), 0, stream,
                       w1, w1TH, w1TL, 3136, 256);
    hipLaunchKernelGGL((k_tsplit<0>), dim3(4, 8), dim3(256), 0, stream,
                       w2, w2TH, w2TL, 256, 512);
    hipLaunchKernelGGL((k_tsplit<0>), dim3(8, 8), dim3(256), 0, stream,
                       w3, w3TH, w3TL, 512, 512);

    // gate = sigmoid(tgt @ a1w + a1b)
    hipLaunchKernelGGL((k_gmfma<2>), dim3(10, 32), dim3(256), 0, stream,
                       tgtH, tgtL, a1wTH, a1wTL, a1b, gate, (ushort_t*)0, (ushort_t*)0,
                       600, 2048, 256);
    // roi + p1
    hipLaunchKernelGGL(k_roip1, dim3(2400), dim3(256), 0, stream,
                       memory, refr, p1w, p1b, roi, pHb, pLb);
    // MLP
    hipLaunchKernelGGL((k_gmfma<0>), dim3(38, 4), dim3(256), 0, stream,
                       pHb, pLb, w1TH, w1TL, b1, (float*)0, h1H, h1L, 2400, 256, 3136);
    hipLaunchKernelGGL((k_gmfma<0>), dim3(38, 8), dim3(256), 0, stream,
                       h1H, h1L, w2TH, w2TL, b2, (float*)0, h2H, h2L, 2400, 512, 256);
    hipLaunchKernelGGL((k_gmfma<1>), dim3(38, 8), dim3(256), 0, stream,
                       h2H, h2L, w3TH, w3TL, b3, h3, (ushort_t*)0, (ushort_t*)0,
                       2400, 512, 512);
    hipLaunchKernelGGL(k_l4, dim3(150), dim3(256), 0, stream, h3, w4, b4, pts);
    hipLaunchKernelGGL(k_sample, dim3(2400), dim3(256), 0, stream,
                       roi, pts, gate, qe);
    hipLaunchKernelGGL(k_out, dim3(600), dim3(256), 0, stream, qe, a2w, a2b, out);
}